// Round 6
// baseline (411.289 us; speedup 1.0000x reference)
//
#include <hip/hip_runtime.h>
#include <hip/hip_bf16.h>

// Problem constants
constexpr int B_   = 8;
constexpr int D_   = 1024;
constexpr int T_   = 512;
constexpr int HID_ = 256;
constexpr int NH_  = 4;
constexpr int NL_  = 2;
constexpr float ALPHA_ = 0.2f;
constexpr float EPS_   = 1e-5f;
constexpr int OUT_ = 64;
constexpr int M_ = B_ * D_;      // 8192 rows
constexpr int DT_ = D_ * T_;     // 524288
constexpr int KIN_ = 2 * T_;     // 1024

typedef __attribute__((ext_vector_type(8))) short short8;   // 8 bf16 (4 VGPRs)
typedef __attribute__((ext_vector_type(4))) float floatx4;  // 4 fp32 acc

__device__ __forceinline__ unsigned short f2bf(float f) {
    unsigned int u = __float_as_uint(f);
    unsigned int r = u + 0x7fffu + ((u >> 16) & 1u);   // round-to-nearest-even
    return (unsigned short)(r >> 16);
}
__device__ __forceinline__ float bf2f(unsigned short u) {
    return __uint_as_float(((unsigned int)u) << 16);
}
// monotone float<->uint key for atomicMax on signed floats
__device__ __forceinline__ unsigned int kenc(float f) {
    unsigned int u = __float_as_uint(f);
    return (u & 0x80000000u) ? ~u : (u | 0x80000000u);
}
__device__ __forceinline__ float kdec(unsigned int k) {
    unsigned int u = (k & 0x80000000u) ? (k ^ 0x80000000u) : ~k;
    return __uint_as_float(u);
}

// ---------------------------------------------------------------------------
// 1) Fused prep: blocks [0,512): imputation -> Ain bf16 [M][1024]=[X_mean|mask]
//    blocks [512,2560): weight transpose/convert + rmaxkey init
// ---------------------------------------------------------------------------
__global__ __launch_bounds__(256) void prep_k(const float* __restrict__ X,
                                              const float* __restrict__ Mk,
                                              const float* __restrict__ W_in,
                                              const float* __restrict__ gatW,
                                              const float* __restrict__ W_out,
                                              unsigned short* __restrict__ Ain,
                                              unsigned short* __restrict__ Wt_in,
                                              unsigned short* __restrict__ Wcat,
                                              unsigned short* __restrict__ WtO,
                                              unsigned int* __restrict__ rmaxkey) {
    int bx = blockIdx.x;
    if (bx < 512) {
        int idx4 = (bx * 256 + threadIdx.x) * 4;   // over D*T
        int t = idx4 & (T_ - 1);
        int d = idx4 >> 9;
        float4 x[B_], m[B_];
        float4 s = {0, 0, 0, 0}, c = {0, 0, 0, 0};
#pragma unroll
        for (int b = 0; b < B_; b++) {
            x[b] = *(const float4*)&X[(size_t)b * DT_ + idx4];
            m[b] = *(const float4*)&Mk[(size_t)b * DT_ + idx4];
            s.x += x[b].x * m[b].x; s.y += x[b].y * m[b].y;
            s.z += x[b].z * m[b].z; s.w += x[b].w * m[b].w;
            c.x += m[b].x; c.y += m[b].y; c.z += m[b].z; c.w += m[b].w;
        }
        float4 pm;
        pm.x = s.x / (c.x + 1e-10f); pm.y = s.y / (c.y + 1e-10f);
        pm.z = s.z / (c.z + 1e-10f); pm.w = s.w / (c.w + 1e-10f);
#pragma unroll
        for (int b = 0; b < B_; b++) {
            size_t row = (size_t)b * D_ + d;
            ushort4 xm, mk;
            xm.x = f2bf(x[b].x * m[b].x + (1.f - m[b].x) * pm.x);
            xm.y = f2bf(x[b].y * m[b].y + (1.f - m[b].y) * pm.y);
            xm.z = f2bf(x[b].z * m[b].z + (1.f - m[b].z) * pm.z);
            xm.w = f2bf(x[b].w * m[b].w + (1.f - m[b].w) * pm.w);
            mk.x = f2bf(m[b].x); mk.y = f2bf(m[b].y);
            mk.z = f2bf(m[b].z); mk.w = f2bf(m[b].w);
            *(ushort4*)&Ain[row * KIN_ + t]      = xm;
            *(ushort4*)&Ain[row * KIN_ + T_ + t] = mk;
        }
    } else {
        int idx = (bx - 512) * 256 + threadIdx.x;
        if (idx < 64) rmaxkey[idx] = 0u;
        if (idx < 262144) {
            int n = idx >> 10, k = idx & 1023;     // Wt_in[n][k] = W_in[k][n]
            Wt_in[idx] = f2bf(W_in[(size_t)k * HID_ + n]);
        } else if (idx < 393216) {
            int j = idx - 262144;
            int l = j >> 16, n = (j >> 8) & 255, k = j & 255;
            int h = n >> 6, e = n & 63;
            Wcat[j] = f2bf(gatW[(((size_t)(l * NH_ + h) * HID_) + k) * OUT_ + e]);
        } else {
            int j = idx - 393216;
            int n = j >> 8, k = j & 255;           // WtO[n][k] = W_out[k][n]
            WtO[j] = f2bf(W_out[(size_t)k * T_ + n]);
        }
    }
}

// ---------------------------------------------------------------------------
// 2) bf16 MFMA GEMM. BM=64 BN=64 BK=64, 4 waves, wave = 16 rows x 64 cols.
//    Padded LDS (stride 72); reg-staged ping-pong.
//    MODE 0: fp32 C (+bias). MODE 1: + bf16 copy.
//    MODE 2: hW [bh][m][e] bf16 via LDS-staged coalesced write + s_l/s_r/rmax.
// ---------------------------------------------------------------------------
template <int MODE>
__global__ __launch_bounds__(256) void gemm_bf16_k(
        const unsigned short* __restrict__ A,    // M x K bf16
        const unsigned short* __restrict__ Bt,   // N x K bf16 (B transposed)
        const float* __restrict__ bias,          // N or null (MODE 0/1)
        float* __restrict__ C,                   // M x N fp32 (MODE 0/1)
        unsigned short* __restrict__ Cb,         // bf16 copy (MODE1) / hwN (MODE2)
        const float* __restrict__ ga,            // gat_a + l*512 (MODE2)
        float* __restrict__ s_l,                 // (MODE2)
        float* __restrict__ s_r,                 // (MODE2)
        unsigned int* __restrict__ rmaxkey,      // + l*32 (MODE2)
        int Nsz, int Ksz) {
    __shared__ __align__(16) unsigned short As[2][64 * 72];  // 18 KB, padded
    __shared__ __align__(16) unsigned short Bs[2][64 * 72];  // 18 KB
    int tid = threadIdx.x;
    int wave = tid >> 6, lane = tid & 63;
    int q = lane >> 4, r16 = lane & 15;
    int rowbase = blockIdx.y * 64;
    int colbase = blockIdx.x * 64;

    int srow = tid >> 3, sk = (tid & 7) * 8;         // staging slot
    const unsigned short* Ap0 = A + (size_t)(rowbase + srow) * Ksz + sk;
    const unsigned short* Ap1 = A + (size_t)(rowbase + srow + 32) * Ksz + sk;
    const unsigned short* Bp0 = Bt + (size_t)(colbase + srow) * Ksz + sk;
    const unsigned short* Bp1 = Bt + (size_t)(colbase + srow + 32) * Ksz + sk;
    int la0 = srow * 72 + sk, la1 = (srow + 32) * 72 + sk;

    floatx4 acc[4];
#pragma unroll
    for (int i = 0; i < 4; i++) acc[i] = (floatx4)0.f;

    uint4 pa0 = *(const uint4*)Ap0, pa1 = *(const uint4*)Ap1;
    uint4 pb0 = *(const uint4*)Bp0, pb1 = *(const uint4*)Bp1;
    *(uint4*)&As[0][la0] = pa0;
    *(uint4*)&As[0][la1] = pa1;
    *(uint4*)&Bs[0][la0] = pb0;
    *(uint4*)&Bs[0][la1] = pb1;

    int nk = Ksz >> 6;
    for (int it = 0; it < nk; it++) {
        int cur = it & 1;
        __syncthreads();
        if (it + 1 < nk) {
            int kt = (it + 1) << 6;
            pa0 = *(const uint4*)(Ap0 + kt);
            pa1 = *(const uint4*)(Ap1 + kt);
            pb0 = *(const uint4*)(Bp0 + kt);
            pb1 = *(const uint4*)(Bp1 + kt);
        }
#pragma unroll
        for (int t = 0; t < 2; t++) {
            short8 a = *(const short8*)&As[cur][(wave * 16 + r16) * 72 + t * 32 + q * 8];
#pragma unroll
            for (int ni = 0; ni < 4; ni++) {
                short8 b = *(const short8*)&Bs[cur][(ni * 16 + r16) * 72 + t * 32 + q * 8];
                acc[ni] = __builtin_amdgcn_mfma_f32_16x16x32_bf16(a, b, acc[ni], 0, 0, 0);
            }
        }
        if (it + 1 < nk) {
            int nxt = cur ^ 1;
            *(uint4*)&As[nxt][la0] = pa0;
            *(uint4*)&As[nxt][la1] = pa1;
            *(uint4*)&Bs[nxt][la0] = pb0;
            *(uint4*)&Bs[nxt][la1] = pb1;
        }
    }
    // ---- epilogue. C/D map: col=lane&15, row=(lane>>4)*4+reg ----
    if constexpr (MODE == 2) {
        int bhh = ((rowbase >> 10) << 2) + blockIdx.x;   // b*4 + h
        int nb0 = rowbase & (D_ - 1);
        int nb = nb0 + wave * 16;
        // fused s_l/s_r from fp32 acc
        const float* gab = ga + blockIdx.x * 2 * OUT_;
        float al4[4], ar4[4];
#pragma unroll
        for (int ni = 0; ni < 4; ni++) {
            al4[ni] = gab[ni * 16 + r16];
            ar4[ni] = gab[OUT_ + ni * 16 + r16];
        }
        float slv[4], srv[4];
#pragma unroll
        for (int rr = 0; rr < 4; rr++) {
            float s1 = 0.f, s2 = 0.f;
#pragma unroll
            for (int ni = 0; ni < 4; ni++) {
                s1 += acc[ni][rr] * al4[ni];
                s2 += acc[ni][rr] * ar4[ni];
            }
            slv[rr] = s1;
            srv[rr] = s2;
        }
#pragma unroll
        for (int off = 1; off < 16; off <<= 1) {
#pragma unroll
            for (int rr = 0; rr < 4; rr++) {
                slv[rr] += __shfl_xor(slv[rr], off, 64);
                srv[rr] += __shfl_xor(srv[rr], off, 64);
            }
        }
        {
            int rsel = r16 & 3;
            float sv = (rsel == 0) ? slv[0] : (rsel == 1) ? slv[1] : (rsel == 2) ? slv[2] : slv[3];
            float rv = (rsel == 0) ? srv[0] : (rsel == 1) ? srv[1] : (rsel == 2) ? srv[2] : srv[3];
            int n = nb + q * 4 + rsel;
            if (r16 < 4)                 s_l[bhh * D_ + n] = sv;
            else if (r16 >= 8 && r16 < 12) s_r[bhh * D_ + n] = rv;
        }
        float mx = fmaxf(fmaxf(srv[0], srv[1]), fmaxf(srv[2], srv[3]));
        mx = fmaxf(mx, __shfl_xor(mx, 16, 64));
        mx = fmaxf(mx, __shfl_xor(mx, 32, 64));
        if (lane == 0) atomicMax(&rmaxkey[bhh], kenc(mx));
        // hwN tile via LDS staging -> coalesced uint4 rows
        __syncthreads();
        unsigned short* st = &As[0][0];
#pragma unroll
        for (int ni = 0; ni < 4; ni++)
#pragma unroll
            for (int rr = 0; rr < 4; rr++)
                st[(wave * 16 + q * 4 + rr) * 72 + ni * 16 + r16] = f2bf(acc[ni][rr]);
        __syncthreads();
#pragma unroll
        for (int i = 0; i < 2; i++) {
            int idx = tid * 2 + i;                 // 64 rows x 8 segs
            int row = idx >> 3, seg = idx & 7;
            uint4 v = *(const uint4*)&st[row * 72 + seg * 8];
            *(uint4*)&Cb[((size_t)bhh << 16) + ((size_t)(nb0 + row) << 6) + seg * 8] = v;
        }
    } else {
#pragma unroll
        for (int rr = 0; rr < 4; rr++) {
            int row = rowbase + wave * 16 + q * 4 + rr;
#pragma unroll
            for (int ni = 0; ni < 4; ni++) {
                int col = colbase + ni * 16 + r16;
                float v = acc[ni][rr] + (bias ? bias[col] : 0.f);
                C[(size_t)row * Nsz + col] = v;
                if constexpr (MODE == 1) Cb[(size_t)row * Nsz + col] = f2bf(v);
            }
        }
    }
}

// ---------------------------------------------------------------------------
// 3) attnfac_k: full factorized attention for one bh in ONE block.
//    1024 threads (16 waves), grid 32. Phases:
//      P0 load sr/sl -> LDS;  bitonic sort (key,idx) ascending (r1-proven);
//      weights w1=exp(sr-rm), w2=exp(a*(sr-rm));
//      P1 per-wave 64-rank sweep, stride-8 RELATIVE checkpoints in LDS;
//      P2 add chunk offsets (exclusive scan over 16 chunk sums);
//         ck[128] = totals (same fp chain => suffix at t=1024 is exact 0);
//      P3 per-row: bsearch t, checkpoint + <=7 fixups,
//         out = (A*(TOT1-P1)+B2*P2)/den  -> hnew[b][n][h*64+e] coalesced.
// ---------------------------------------------------------------------------
__global__ __launch_bounds__(1024) void attnfac_k(
        const unsigned short* __restrict__ hwN,   // [32][1024][64] bf16
        const float* __restrict__ sl_g,           // [32][1024]
        const float* __restrict__ sr_g,           // [32][1024]
        const unsigned int* __restrict__ rmaxkey, // +l*32
        float* __restrict__ hnew) {               // [8][1024][256] fp32
    __shared__ float srtL[1024];                  // 4 KB (sorted keys)
    __shared__ unsigned short sidxL[1024];        // 2 KB (orig index)
    __shared__ float ws1[1024], ws2[1024];        // 8 KB
    __shared__ float slL[1024];                   // 4 KB
    __shared__ float ck1[129][64], ck2[129][64];  // 64.5 KB stride-8 ckpts
    __shared__ float ckp[129][2];                 // 1 KB scalar ckpts
    __shared__ float csum1[16][64], csum2[16][64];// 8 KB chunk sums
    __shared__ float csca[16][2];

    int bh = blockIdx.x, tid = threadIdx.x;
    int wv = tid >> 6, e = tid & 63;
    float rm = kdec(rmaxkey[bh]);

    // P0: load
    srtL[tid] = sr_g[bh * D_ + tid];
    sidxL[tid] = (unsigned short)tid;
    slL[tid] = sl_g[bh * D_ + tid];
    __syncthreads();
    // bitonic sort ascending on (srtL, sidxL)
    for (int k = 2; k <= 1024; k <<= 1) {
        for (int j = k >> 1; j > 0; j >>= 1) {
            int t = tid, ixj = t ^ j;
            if (ixj > t) {
                bool up = ((t & k) == 0);
                float a = srtL[t], b2 = srtL[ixj];
                bool sw = up ? (a > b2) : (a < b2);
                if (sw) {
                    srtL[t] = b2; srtL[ixj] = a;
                    unsigned short ti = sidxL[t]; sidxL[t] = sidxL[ixj]; sidxL[ixj] = ti;
                }
            }
            __syncthreads();
        }
    }
    // weights at rank position
    {
        float u = srtL[tid] - rm;                 // <= 0
        ws1[tid] = __expf(u);
        ws2[tid] = __expf(ALPHA_ * u);
    }
    __syncthreads();

    const unsigned short* vb = hwN + ((size_t)bh << 16);
    // P1: relative sweep, stride-8 checkpoints
    {
        float a1 = 0.f, a2 = 0.f, q1 = 0.f, q2 = 0.f;
        int t0 = wv * 64;
        for (int j = 0; j < 64; ++j) {
            int t = t0 + j;
            if ((j & 7) == 0) {
                int tc = wv * 8 + (j >> 3);
                ck1[tc][e] = a1; ck2[tc][e] = a2;
                if (e == 0) { ckp[tc][0] = q1; ckp[tc][1] = q2; }
            }
            float w1 = ws1[t], w2 = ws2[t];
            float v = bf2f(vb[((size_t)sidxL[t] << 6) + e]);
            a1 = fmaf(w1, v, a1);
            a2 = fmaf(w2, v, a2);
            q1 += w1; q2 += w2;
        }
        csum1[wv][e] = a1; csum2[wv][e] = a2;
        if (e == 0) { csca[wv][0] = q1; csca[wv][1] = q2; }
    }
    __syncthreads();
    // P2: add exclusive chunk offsets
    {
        float o1 = 0.f, o2 = 0.f, op1 = 0.f, op2 = 0.f;
        for (int cc = 0; cc < wv; ++cc) {
            o1 += csum1[cc][e]; o2 += csum2[cc][e];
            op1 += csca[cc][0]; op2 += csca[cc][1];
        }
#pragma unroll
        for (int j = 0; j < 8; ++j) {
            ck1[wv * 8 + j][e] += o1;
            ck2[wv * 8 + j][e] += o2;
        }
        if (e < 8) {
            ckp[wv * 8 + e][0] += op1;
            ckp[wv * 8 + e][1] += op2;
        }
        if (wv == 15) {
            ck1[128][e] = o1 + csum1[15][e];
            ck2[128][e] = o2 + csum2[15][e];
            if (e == 0) {
                ckp[128][0] = op1 + csca[15][0];
                ckp[128][1] = op2 + csca[15][1];
            }
        }
    }
    __syncthreads();
    // P3: emission, 64 rows per wave, lane = e
    int b = bh >> 2, h4 = bh & 3;
    float qT1 = ckp[128][0];
    float TOT1 = ck1[128][e];
    for (int j = 0; j < 64; ++j) {
        int n = wv * 64 + j;
        float sl = slL[n];
        float x = sl + rm;
        float Mn = fmaxf(x, ALPHA_ * x);          // = max_m e[n,m]
        float A  = __expf(x - Mn);
        float B2 = __expf(ALPHA_ * x - Mn);
        float key = -sl;
        int lo = 0, hi = 1024;
        while (lo < hi) {
            int mid = (lo + hi) >> 1;
            if (srtL[mid] < key) lo = mid + 1; else hi = mid;
        }
        int t = lo, c8 = t >> 3, nf = t & 7;
        float P1 = ck1[c8][e], P2 = ck2[c8][e];
        float qp1 = ckp[c8][0], qp2 = ckp[c8][1];
        for (int f = 0; f < nf; ++f) {
            int rk = (c8 << 3) + f;
            float w1 = ws1[rk], w2 = ws2[rk];
            float v = bf2f(vb[((size_t)sidxL[rk] << 6) + e]);
            P1 = fmaf(w1, v, P1);
            P2 = fmaf(w2, v, P2);
            qp1 += w1; qp2 += w2;
        }
        float den = A * (qT1 - qp1) + B2 * qp2;   // >= exp(0) = 1
        float inv = 1.f / den;
        float outv = (A * (TOT1 - P1) + B2 * P2) * inv;
        hnew[(((size_t)b << 10) + n) * HID_ + h4 * OUT_ + e] = outv;
    }
}

// ---------------------------------------------------------------------------
// 4) addln2_k: h = LayerNorm(h + hnew)*g + b; fp32 + bf16 out.
//    One wave per row, shfl-only reductions. grid 2048 x 256.
// ---------------------------------------------------------------------------
__global__ __launch_bounds__(256) void addln2_k(float* __restrict__ h,
                                                const float* __restrict__ hnew,
                                                const float* __restrict__ g,
                                                const float* __restrict__ bb,
                                                unsigned short* __restrict__ hbf) {
    int wave = threadIdx.x >> 6, lane = threadIdx.x & 63;
    size_t row = (size_t)blockIdx.x * 4 + wave;
    float4 a  = *(const float4*)&h[row * HID_ + lane * 4];
    float4 nv = *(const float4*)&hnew[row * HID_ + lane * 4];
    float4 v = {a.x + nv.x, a.y + nv.y, a.z + nv.z, a.w + nv.w};
    float s = v.x + v.y + v.z + v.w;
#pragma unroll
    for (int off = 1; off < 64; off <<= 1) s += __shfl_xor(s, off, 64);
    float mu = s * (1.f / HID_);
    float4 d = {v.x - mu, v.y - mu, v.z - mu, v.w - mu};
    float s2 = d.x * d.x + d.y * d.y + d.z * d.z + d.w * d.w;
#pragma unroll
    for (int off = 1; off < 64; off <<= 1) s2 += __shfl_xor(s2, off, 64);
    float rs = rsqrtf(s2 * (1.f / HID_) + EPS_);
    float4 gg = *(const float4*)&g[lane * 4];
    float4 bbv = *(const float4*)&bb[lane * 4];
    float4 res;
    res.x = d.x * rs * gg.x + bbv.x;
    res.y = d.y * rs * gg.y + bbv.y;
    res.z = d.z * rs * gg.z + bbv.z;
    res.w = d.w * rs * gg.w + bbv.w;
    *(float4*)&h[row * HID_ + lane * 4] = res;
    ushort4 pk = {f2bf(res.x), f2bf(res.y), f2bf(res.z), f2bf(res.w)};
    *(ushort4*)&hbf[row * HID_ + lane * 4] = pk;
}

// ---------------------------------------------------------------------------
extern "C" void kernel_launch(void* const* d_in, const int* in_sizes, int n_in,
                              void* d_out, int out_size, void* d_ws, size_t ws_size,
                              hipStream_t stream) {
    const float* X_obs = (const float*)d_in[0];
    const float* mask  = (const float*)d_in[1];
    const float* W_in  = (const float*)d_in[2];
    const float* b_in  = (const float*)d_in[3];
    const float* gat_W = (const float*)d_in[4];
    const float* gat_a = (const float*)d_in[5];
    const float* ln_g  = (const float*)d_in[6];
    const float* ln_b  = (const float*)d_in[7];
    const float* W_out = (const float*)d_in[8];
    const float* b_out = (const float*)d_in[9];
    float* out = (float*)d_out;

    // Workspace layout:
    //  [0,16M):   Ain bf16 (M x 1024), dead after gemm1; then:
    //             hwN bf16 [32][1024][64] at [0,4M), hnew fp32 [M][256] at [4,12M)
    //  [23M,31M): hbuf fp32 (M x 256)
    //  [31M,35M): hbf bf16 (M x 256)
    //  [35M,+):   Wt_in, Wcat, WtO (bf16), slb/srb (fp32), rmaxkey (uint[64])
    char* base = (char*)d_ws;
    unsigned short* Ain = (unsigned short*)base;
    unsigned short* hwN = (unsigned short*)base;
    float* hnew = (float*)(base + (4u << 20));
    float* hbuf = (float*)(base + (23u << 20));
    unsigned short* hbf   = (unsigned short*)(base + (31u << 20));
    unsigned short* Wt_in = (unsigned short*)(base + (35u << 20));
    unsigned short* Wcat  = Wt_in + (size_t)HID_ * KIN_;        // 256*1024
    unsigned short* WtO   = Wcat + (size_t)NL_ * HID_ * HID_;   // 2*256*256
    float* slb = (float*)(WtO + (size_t)T_ * HID_);             // 32*1024
    float* srb = slb + B_ * NH_ * D_;
    unsigned int* rmaxkey = (unsigned int*)(srb + B_ * NH_ * D_);  // [2][32]

    prep_k<<<2560, 256, 0, stream>>>(X_obs, mask, W_in, gat_W, W_out,
                                     Ain, Wt_in, Wcat, WtO, rmaxkey);

    // h = [X_mean|mask] @ W_in + b_in   (8192x1024)@(1024x256), fp32+bf16 out
    gemm_bf16_k<1><<<dim3(HID_ / 64, M_ / 64), 256, 0, stream>>>(
        Ain, Wt_in, b_in, hbuf, hbf, nullptr, nullptr, nullptr, nullptr,
        HID_, KIN_);

    for (int l = 0; l < NL_; l++) {
        // hW = h @ Wcat[l] -> hwN [bh][m][e] bf16 + fused s_l/s_r/rmax
        gemm_bf16_k<2><<<dim3(HID_ / 64, M_ / 64), 256, 0, stream>>>(
            hbf, Wcat + (size_t)l * HID_ * HID_, nullptr, nullptr, hwN,
            gat_a + (size_t)l * NH_ * 2 * OUT_, slb, srb, rmaxkey + l * 32,
            HID_, HID_);
        // factorized attention: sort + prefix + emission, all in-LDS per bh
        attnfac_k<<<32, 1024, 0, stream>>>(hwN, slb, srb, rmaxkey + l * 32,
                                           hnew);
        // fused residual + LayerNorm
        addln2_k<<<M_ / 4, 256, 0, stream>>>(hbuf, hnew,
                                             ln_g + (size_t)l * HID_,
                                             ln_b + (size_t)l * HID_, hbf);
    }

    // out = h @ W_out + b_out  (8192x256)@(256x512), fp32 out
    gemm_bf16_k<0><<<dim3(T_ / 64, M_ / 64), 256, 0, stream>>>(
        hbf, WtO, b_out, out, nullptr, nullptr, nullptr, nullptr, nullptr,
        T_, HID_);
}